// Round 1
// 75.093 us; speedup vs baseline: 1.0464x; 1.0464x over previous
//
#include <hip/hip_runtime.h>

#define KK 16
#define NPIX 16384   // 128*128

// ws layout (no zero-init required — K1 initializes acc/cnt, partials are overwritten):
//   [0    .. 1023]  : int    maxpart[256]  per-block D2 max, index = b*128 + k*8 + rg
//   [1024 .. 1027]  : float  acc           loss accumulator   (K1 inits to 0)
//   [1028 .. 1031]  : uint   cnt           ticket counter     (K1 inits to 0)
//   [4096 .. +1MB]  : u16    d2[2*16*16384] squared EDT per (b,k,pixel), <= 40000

__global__ __launch_bounds__(256) void edt_kernel(const int* __restrict__ mask,
                                                  int* __restrict__ maxpart,
                                                  float* __restrict__ acc,
                                                  unsigned int* __restrict__ cnt,
                                                  unsigned short* __restrict__ d2) {
    __shared__ alignas(16) unsigned char  nuc[NPIX];      // 16 KB
    __shared__ alignas(16) unsigned short sdn[NPIX];      // 32 KB: down-dist, then nd^2 (G2)
    __shared__ alignas(16) unsigned short sup[NPIX];      // 32 KB: up-dist
    __shared__ int wmax[4];

    const int bid = blockIdx.x;       // 0..255
    const int t   = threadIdx.x;      // 0..255
    const int b1  = bid >> 7;         // 0..1
    const int k1  = (bid >> 3) & 15;  // 0..15
    const int rg  = bid & 7;          // 0..7

    if (bid == 0 && t == 0) { *acc = 0.0f; *cnt = 0u; }  // init for K2
                                                         // (kernel boundary = visibility)

    // ---- stage nuclei bytes (int4 mask loads) ----
    const int label = k1 + 1;
    const int4* m4 = (const int4*)(mask + b1 * NPIX);
    #pragma unroll
    for (int it = 0; it < 16; ++it) {
        const int idx = t + 256 * it;          // 0..4095
        const int4 v = m4[idx];
        uchar4 u;
        u.x = (v.x == label); u.y = (v.y == label);
        u.z = (v.z == label); u.w = (v.w == label);
        *(uchar4*)&nuc[idx * 4] = u;
    }
    __syncthreads();

    // ---- concurrent down/up 1D column scans (sentinel 200) ----
    if (t < 128) {
        const int j = t;
        int dist = 200;
        #pragma unroll 4
        for (int i = 0; i < 128; ++i) {
            dist = nuc[i * 128 + j] ? min(dist + 1, 200) : 0;
            sdn[i * 128 + j] = (unsigned short)dist;
        }
    } else {
        const int j = t - 128;
        int dist = 200;
        #pragma unroll 4
        for (int i = 127; i >= 0; --i) {
            dist = nuc[i * 128 + j] ? min(dist + 1, 200) : 0;
            sup[i * 128 + j] = (unsigned short)dist;
        }
    }
    __syncthreads();

    // ---- combine: G2 = min(down,up)^2 (<= 40000, fits u16) ----
    #pragma unroll
    for (int it = 0; it < 64; ++it) {
        const int idx = t + 256 * it;
        const int nd = min((int)sdn[idx], (int)sup[idx]);
        sdn[idx] = (unsigned short)(nd * nd);
    }
    __syncthreads();

    // ---- windowed row pass: D2[j] = min_jp( G2[jp] + (j-jp)^2 ) ----
    // Exact: after evaluating jp in [c0-e, c0+7+e], every unevaluated candidate
    // contributes >= (e+1)^2; stop once that can't beat any of the lane's 8 bests.
    // Random-label data => G2 tiny => typical trip count ~3-6 instead of 128.
    const int row = rg * 16 + (t >> 4);
    const int c0  = (t & 15) * 8;
    const unsigned short* grow = &sdn[row * 128];

    // initial window jp in [c0, c0+7]: one 16B LDS read, dj^2 are compile-time consts
    const uint4 gv = *(const uint4*)(grow + c0);
    int g[8];
    g[0] = (int)(gv.x & 0xffffu); g[1] = (int)(gv.x >> 16);
    g[2] = (int)(gv.y & 0xffffu); g[3] = (int)(gv.y >> 16);
    g[4] = (int)(gv.z & 0xffffu); g[5] = (int)(gv.z >> 16);
    g[6] = (int)(gv.w & 0xffffu); g[7] = (int)(gv.w >> 16);

    int best[8];
    #pragma unroll
    for (int u = 0; u < 8; ++u) best[u] = 0x7fffffff;
    #pragma unroll
    for (int w = 0; w < 8; ++w) {
        #pragma unroll
        for (int u = 0; u < 8; ++u) {
            const int dj = u - w;                 // compile-time constant
            best[u] = min(best[u], g[w] + dj * dj);
        }
    }
    int mb = 0;
    #pragma unroll
    for (int u = 0; u < 8; ++u) mb = max(mb, best[u]);

    // expand outward; wave-uniform trip count via __any vote
    for (int e = 0; e < 128; ++e) {
        if (!__any((e + 1) * (e + 1) < mb)) break;
        const int jl = c0 - 1 - e;
        const int jr = c0 + 8 + e;
        if (jl >= 0) {
            const int gl = (int)grow[jl];
            #pragma unroll
            for (int u = 0; u < 8; ++u) {
                const int dj = u + 1 + e;         // (c0+u) - jl
                best[u] = min(best[u], gl + dj * dj);
            }
        }
        if (jr < 128) {
            const int gr = (int)grow[jr];
            #pragma unroll
            for (int u = 0; u < 8; ++u) {
                const int dj = 8 + e - u;         // jr - (c0+u)
                best[u] = min(best[u], gr + dj * dj);
            }
        }
        mb = 0;
        #pragma unroll
        for (int u = 0; u < 8; ++u) mb = max(mb, best[u]);
    }

    // pack 8 u16 D2 values -> one 16B store (values <= 40000 fit u16)
    uint4 w;
    w.x = (unsigned)best[0] | ((unsigned)best[1] << 16);
    w.y = (unsigned)best[2] | ((unsigned)best[3] << 16);
    w.z = (unsigned)best[4] | ((unsigned)best[5] << 16);
    w.w = (unsigned)best[6] | ((unsigned)best[7] << 16);
    *(uint4*)(d2 + (b1 * KK + k1) * NPIX + row * 128 + c0) = w;

    // block max of D2 (mb is already this lane's max over its 8 columns)
    int bm = mb;
    #pragma unroll
    for (int off = 32; off; off >>= 1) bm = max(bm, __shfl_down(bm, off, 64));
    if ((t & 63) == 0) wmax[t >> 6] = bm;
    __syncthreads();
    if (t == 0)
        maxpart[bid] = max(max(wmax[0], wmax[1]), max(wmax[2], wmax[3]));
}

// Disjoint-support gt+loss: each pixel belongs to at most ONE instance, so gt has
// exactly one nonzero channel, selected by the pixel's own label.
// 256 blocks x 128 threads: one block per CU (was 128 blocks -> half the CUs idle).
__global__ __launch_bounds__(128) void gt_loss_kernel(const float* __restrict__ pred,
                                                      const float* __restrict__ ign,
                                                      const int* __restrict__ mask,
                                                      const unsigned short* __restrict__ d2,
                                                      const int* __restrict__ maxpart,
                                                      float* __restrict__ out,
                                                      float* __restrict__ acc,
                                                      unsigned int* __restrict__ cnt) {
    __shared__ float msq[KK];
    __shared__ float wred[2];

    const int bid = blockIdx.x;           // 0..255
    const int t   = threadIdx.x;          // 0..127
    const int p   = bid * 128 + t;        // global pixel 0..32767
    const int b   = bid >> 7;             // 0..1  (all pixels of a block share b)
    const int pp  = p & (NPIX - 1);

    // msq[k] = sqrt(max D2) for this b (reduce the 8 row-group partials)
    if (t < KK) {
        const int base = b * 128 + t * 8;
        int mt = 0;
        #pragma unroll
        for (int r = 0; r < 8; ++r) mt = max(mt, maxpart[base + r]);
        msq[t] = __fsqrt_rn((float)mt);
    }
    __syncthreads();

    const int label = mask[p];
    int cbin = -1;                        // which gt channel is 1 (none if bg)
    if (label > 0) {
        const int k = label - 1;
        const float d  = __fsqrt_rn((float)d2[(b * KK + k) * NPIX + pp]);  // D2>=1
        float dn = __fdiv_rn(d, msq[k]);  // msq >= 1 since maxD2 >= D2 >= 1
        if (dn < 0.5f) dn = 0.0f;
        if (dn > 0.7f) dn = 1.0f;
        const float ddd[8] = {0.83f, 0.68f, 0.54f, 0.41f, 0.29f, 0.18f, 0.09f, 0.0f};
        #pragma unroll
        for (int c = 0; c < 8; ++c) {
            if (cbin < 0 && dn >= ddd[c]) cbin = c;
        }
    }

    float lsum = 0.0f;
    #pragma unroll
    for (int c = 0; c < 8; ++c) {
        const float g = (c == cbin) ? 1.0f : 0.0f;
        out[1 + (b * 8 + c) * NPIX + pp] = g;
        const float diff = pred[(b * 8 + c) * NPIX + pp] - g;
        const float ad = fabsf(diff);
        lsum += (ad < 1.0f) ? 0.5f * diff * diff : (ad - 0.5f);
    }
    float contrib = lsum * 0.125f * ign[p];

    #pragma unroll
    for (int off = 32; off; off >>= 1) contrib += __shfl_down(contrib, off, 64);
    if ((t & 63) == 0) wred[t >> 6] = contrib;
    __syncthreads();

    if (t == 0) {
        atomicAdd(acc, wred[0] + wred[1]);
        __threadfence();
        const unsigned int old = atomicAdd(cnt, 1u);
        if (old == 255u) {                        // last block: all adds visible
            const float total = atomicAdd(acc, 0.0f);
            out[0] = total * (1.0f / 32768.0f);
        }
    }
}

extern "C" void kernel_launch(void* const* d_in, const int* in_sizes, int n_in,
                              void* d_out, int out_size, void* d_ws, size_t ws_size,
                              hipStream_t stream) {
    const float* pred = (const float*)d_in[0];
    const int*   mask = (const int*)d_in[1];
    const float* ign  = (const float*)d_in[2];
    float* out = (float*)d_out;

    int*            maxpart = (int*)d_ws;
    float*          acc     = (float*)((char*)d_ws + 1024);
    unsigned int*   cnt     = (unsigned int*)((char*)d_ws + 1028);
    unsigned short* d2      = (unsigned short*)((char*)d_ws + 4096);

    edt_kernel<<<256, 256, 0, stream>>>(mask, maxpart, acc, cnt, d2);
    gt_loss_kernel<<<256, 128, 0, stream>>>(pred, ign, mask, d2, maxpart, out, acc, cnt);
}